// Round 3
// baseline (2562.026 us; speedup 1.0000x reference)
//
#include <hip/hip_runtime.h>
#include <stdint.h>

// Problem constants (B=256, L=2048, H=64, TE=64)
#define NB 256
#define NL 2048
#define NM (NB*NL)   // 524288 positions

// ---------- bf16 helpers (manual, RNE) ----------
static __device__ __forceinline__ unsigned short f2bf(float f) {
    union { float f; uint32_t u; } v; v.f = f;
    uint32_t u = v.u;
    uint32_t r = u + 0x7fffu + ((u >> 16) & 1u);
    return (unsigned short)(r >> 16);
}
static __device__ __forceinline__ float bflo(uint32_t u) {
    union { uint32_t u; float f; } v; v.u = u << 16; return v.f;
}
static __device__ __forceinline__ float bfhi(uint32_t u) {
    union { uint32_t u; float f; } v; v.u = u & 0xffff0000u; return v.f;
}

// ---------- per-direction proj + gates, weights in LDS (stride-68 proj rows) ----------
static __device__ __forceinline__ void do_dir(
    const float* __restrict__ pw, const float* __restrict__ pb,   // LDS proj [64][68],[64]
    const float* __restrict__ wz, const float* __restrict__ bz,   // LDS [64][64],[64]
    const float* __restrict__ wh, const float* __restrict__ bh,
    const float (&tenc)[64], float x0, float x1, float mc,
    uint32_t* __restrict__ dst /* + o*NL strided */)
{
    float inp[64];
#pragma unroll 2
    for (int o = 0; o < 64; ++o) {
        float acc = pb[o];
        acc = fmaf(x0, pw[o*68+0], acc);
        acc = fmaf(x1, pw[o*68+1], acc);
        acc = fmaf(mc, pw[o*68+2], acc);
#pragma unroll
        for (int k = 0; k < 64; ++k) acc = fmaf(tenc[k], pw[o*68+3+k], acc);
        inp[o] = acc;
    }
#pragma unroll 2
    for (int o = 0; o < 64; ++o) {
        float az = bz[o], ah = bh[o];
#pragma unroll
        for (int k = 0; k < 64; ++k) {
            az = fmaf(inp[k], wz[o*64+k], az);
            ah = fmaf(inp[k], wh[o*64+k], ah);
        }
        float z  = 1.f / (1.f + __expf(-az));
        float c  = fminf(fmaxf(ah, -15.f), 15.f);
        float e  = __expf(2.f * c);
        float th = (e - 1.f) / (e + 1.f);
        float av = 1.f - z;
        float bv = z * th;
        dst[(size_t)o * NL] = ((uint32_t)f2bf(bv) << 16) | (uint32_t)f2bf(av);
    }
}

// LDS float offsets for prep weights
#define O_TEW1 0
#define O_TEB1 64
#define O_TEW2 128
#define O_TEB2 4224
#define O_FPW  4288     // 64x68 padded
#define O_FPB  8640
#define O_BPW  8704     // 64x68 padded
#define O_BPB  13056
#define O_FWZ  13120
#define O_FBZ  17216
#define O_FWH  17280
#define O_FBH  21376
#define O_BWZ  21440
#define O_BBZ  25536
#define O_BWH  25600
#define O_BBH  29696
#define PREP_LDS 29760  // floats (119,040 B)

// ---------- kernel 1: time-MLP + proj + gates -> packed (a,b) bf16, [b_local][h][l] ----------
// grid = 2*Bg blocks; each block: 1024 positions in 4 chunks of 256
__global__ __launch_bounds__(256, 1) void prep_kernel(
    const float* __restrict__ x, const float* __restrict__ t,
    const float* __restrict__ mtok,
    const float* __restrict__ te_w1, const float* __restrict__ te_b1,
    const float* __restrict__ te_w2, const float* __restrict__ te_b2,
    const float* __restrict__ fpw, const float* __restrict__ fpb,
    const float* __restrict__ bpw, const float* __restrict__ bpb,
    const float* __restrict__ fwz, const float* __restrict__ fbz,
    const float* __restrict__ fwh, const float* __restrict__ fbh,
    const float* __restrict__ bwz, const float* __restrict__ bbz,
    const float* __restrict__ bwh, const float* __restrict__ bbh,
    int b0,
    unsigned short* __restrict__ tenc_out,   // [Bg*L,64] bf16 (group-local)
    uint32_t* __restrict__ abf,              // [Bg*64, L] packed (a lo, b hi)
    uint32_t* __restrict__ abb)
{
    __shared__ float sw[PREP_LDS];
    const int tid = threadIdx.x;

    // ---- cooperative weight staging ----
#pragma unroll 1
    for (int i = tid; i < 64;   i += 256) sw[O_TEW1+i] = te_w1[i];
#pragma unroll 1
    for (int i = tid; i < 64;   i += 256) sw[O_TEB1+i] = te_b1[i];
#pragma unroll 1
    for (int i = tid; i < 4096; i += 256) sw[O_TEW2+i] = te_w2[i];
#pragma unroll 1
    for (int i = tid; i < 64;   i += 256) sw[O_TEB2+i] = te_b2[i];
#pragma unroll 1
    for (int i = tid; i < 4288; i += 256) { int o = i / 67, c = i % 67; sw[O_FPW + o*68 + c] = fpw[i]; }
#pragma unroll 1
    for (int i = tid; i < 64;   i += 256) sw[O_FPB+i] = fpb[i];
#pragma unroll 1
    for (int i = tid; i < 4288; i += 256) { int o = i / 67, c = i % 67; sw[O_BPW + o*68 + c] = bpw[i]; }
#pragma unroll 1
    for (int i = tid; i < 64;   i += 256) sw[O_BPB+i] = bpb[i];
#pragma unroll 1
    for (int i = tid; i < 4096; i += 256) sw[O_FWZ+i] = fwz[i];
#pragma unroll 1
    for (int i = tid; i < 64;   i += 256) sw[O_FBZ+i] = fbz[i];
#pragma unroll 1
    for (int i = tid; i < 4096; i += 256) sw[O_FWH+i] = fwh[i];
#pragma unroll 1
    for (int i = tid; i < 64;   i += 256) sw[O_FBH+i] = fbh[i];
#pragma unroll 1
    for (int i = tid; i < 4096; i += 256) sw[O_BWZ+i] = bwz[i];
#pragma unroll 1
    for (int i = tid; i < 64;   i += 256) sw[O_BBZ+i] = bbz[i];
#pragma unroll 1
    for (int i = tid; i < 4096; i += 256) sw[O_BWH+i] = bwh[i];
#pragma unroll 1
    for (int i = tid; i < 64;   i += 256) sw[O_BBH+i] = bbh[i];
    __syncthreads();

    const float mt0 = mtok[0], mt1 = mtok[1];

#pragma unroll 1
    for (int c = 0; c < 4; ++c) {
        const int posl = blockIdx.x * 1024 + c * 256 + tid;
        const int bl   = posl >> 11;
        const int ll   = posl & 2047;
        const int gpos = (b0 << 11) + posl;

        const float tv = t[gpos];
        float te1[64];
#pragma unroll
        for (int k = 0; k < 64; ++k)
            te1[k] = fmaxf(fmaf(tv, sw[O_TEW1+k], sw[O_TEB1+k]), 0.f);

        float tenc[64];
#pragma unroll 4
        for (int o = 0; o < 64; ++o) {
            float acc = sw[O_TEB2+o];
#pragma unroll
            for (int k = 0; k < 64; ++k) acc = fmaf(te1[k], sw[O_TEW2 + o*64 + k], acc);
            tenc[o] = acc;
        }
        // packed bf16 tenc store (8 at a time)
        {
            uint32_t* tp = (uint32_t*)(tenc_out + (size_t)posl * 64);
#pragma unroll
            for (int o = 0; o < 64; o += 2)
                tp[o >> 1] = ((uint32_t)f2bf(tenc[o+1]) << 16) | (uint32_t)f2bf(tenc[o]);
        }

        const float mc = x[(size_t)gpos*3+2];
        const bool masked = (mc == 0.f);
        const float x0 = masked ? mt0 : x[(size_t)gpos*3+0];
        const float x1 = masked ? mt1 : x[(size_t)gpos*3+1];

        uint32_t* dstf = abf + (size_t)(bl * 64) * NL + ll;
        uint32_t* dstb = abb + (size_t)(bl * 64) * NL + ll;
        do_dir(sw+O_FPW, sw+O_FPB, sw+O_FWZ, sw+O_FBZ, sw+O_FWH, sw+O_FBH,
               tenc, x0, x1, mc, dstf);
        do_dir(sw+O_BPW, sw+O_BPB, sw+O_BWZ, sw+O_BBZ, sw+O_BWH, sw+O_BBH,
               tenc, x0, x1, mc, dstb);
    }
}

// ---------- kernel 2: 2*Bg*64 independent linear scans ----------
__global__ __launch_bounds__(64) void scan_kernel(
    const uint32_t* __restrict__ abf, const uint32_t* __restrict__ abb,
    int Bg,
    unsigned short* __restrict__ hf, unsigned short* __restrict__ hb) // [b_l][l][h] bf16
{
    const int tid = blockIdx.x * 64 + threadIdx.x;   // 0 .. 2*Bg*64-1
    const int nfw = Bg * 64;
    const int dir = (tid >= nfw) ? 1 : 0;
    const int bh  = tid - dir * nfw;                 // group-local b*64+h
    const int bl  = bh >> 6;
    const int hh  = bh & 63;

    const uint32_t* ab = (dir ? abb : abf) + (size_t)bh * NL;
    unsigned short* out = (dir ? hb : hf) + (size_t)bl * NL * 64 + hh;

    float hv = 0.f;
    if (dir == 0) {
#pragma unroll 1
        for (int l0 = 0; l0 < NL; l0 += 32) {
            const uint4* p = (const uint4*)(ab + l0);
            uint4 v[8];
#pragma unroll
            for (int i = 0; i < 8; ++i) v[i] = p[i];
            uint32_t q[32];
#pragma unroll
            for (int i = 0; i < 8; ++i) {
                q[4*i+0]=v[i].x; q[4*i+1]=v[i].y; q[4*i+2]=v[i].z; q[4*i+3]=v[i].w;
            }
            unsigned short* op = out + (size_t)l0 * 64;
#pragma unroll
            for (int i = 0; i < 32; ++i) {
                *op = f2bf(hv); op += 64;
                hv = fmaf(bflo(q[i]), hv, bfhi(q[i]));   // h = a*h + b
            }
        }
    } else {
#pragma unroll 1
        for (int l0 = NL - 32; l0 >= 0; l0 -= 32) {
            const uint4* p = (const uint4*)(ab + l0);
            uint4 v[8];
#pragma unroll
            for (int i = 0; i < 8; ++i) v[i] = p[i];
            uint32_t q[32];
#pragma unroll
            for (int i = 0; i < 8; ++i) {
                q[4*i+0]=v[i].x; q[4*i+1]=v[i].y; q[4*i+2]=v[i].z; q[4*i+3]=v[i].w;
            }
            unsigned short* op = out + (size_t)(l0 + 31) * 64;
#pragma unroll
            for (int i = 31; i >= 0; --i) {
                *op = f2bf(hv); op -= 64;
                hv = fmaf(bflo(q[i]), hv, bfhi(q[i]));
            }
        }
    }
}

// ---------- kernel 3: head GEMM (192 -> 128 relu -> 1), w1 in LDS ----------
// grid = 2*Bg blocks; each block: 1024 positions in 4 chunks of 256
__global__ __launch_bounds__(256, 1) void head_kernel(
    const float* __restrict__ x,
    const unsigned short* __restrict__ tenc,
    const unsigned short* __restrict__ hf, const unsigned short* __restrict__ hb,
    const float* __restrict__ w1, const float* __restrict__ b1,  // [128,192],[128]
    const float* __restrict__ w2, const float* __restrict__ b2,  // [1,128],[1]
    int b0,
    float* __restrict__ out)
{
    __shared__ float sh[24576 + 128 + 128];   // w1 | b1 | w2
    const int tid = threadIdx.x;
#pragma unroll 1
    for (int i = tid; i < 6144; i += 256) ((float4*)sh)[i] = ((const float4*)w1)[i];
#pragma unroll 1
    for (int i = tid; i < 128; i += 256) sh[24576 + i] = b1[i];
#pragma unroll 1
    for (int i = tid; i < 128; i += 256) sh[24704 + i] = w2[i];
    __syncthreads();
    const float bias2 = b2[0];

#pragma unroll 1
    for (int c = 0; c < 4; ++c) {
        const int posl = blockIdx.x * 1024 + c * 256 + tid;
        const int bl   = posl >> 11;
        const int ll   = posl & 2047;
        const int gpos = (b0 << 11) + posl;

        const float mc = x[(size_t)gpos*3+2];
        const bool unm = (mc > 0.f);
        const size_t rowbase = (size_t)bl * NL * 64;
        const uint4* pf = (const uint4*)(hf + rowbase + (size_t)(unm ? ll : (NL-1)) * 64);
        const uint4* pb = (const uint4*)(hb + rowbase + (size_t)(unm ? ll : 0) * 64);
        const uint4* pt = (const uint4*)(tenc + (size_t)posl * 64);

        float abi[192];
#pragma unroll
        for (int i = 0; i < 8; ++i) {
            uint4 q = pf[i];
            abi[i*8+0]=bflo(q.x); abi[i*8+1]=bfhi(q.x);
            abi[i*8+2]=bflo(q.y); abi[i*8+3]=bfhi(q.y);
            abi[i*8+4]=bflo(q.z); abi[i*8+5]=bfhi(q.z);
            abi[i*8+6]=bflo(q.w); abi[i*8+7]=bfhi(q.w);
        }
#pragma unroll
        for (int i = 0; i < 8; ++i) {
            uint4 q = pb[i];
            abi[64+i*8+0]=bflo(q.x); abi[64+i*8+1]=bfhi(q.x);
            abi[64+i*8+2]=bflo(q.y); abi[64+i*8+3]=bfhi(q.y);
            abi[64+i*8+4]=bflo(q.z); abi[64+i*8+5]=bfhi(q.z);
            abi[64+i*8+6]=bflo(q.w); abi[64+i*8+7]=bfhi(q.w);
        }
#pragma unroll
        for (int i = 0; i < 8; ++i) {
            uint4 q = pt[i];
            abi[128+i*8+0]=bflo(q.x); abi[128+i*8+1]=bfhi(q.x);
            abi[128+i*8+2]=bflo(q.y); abi[128+i*8+3]=bfhi(q.y);
            abi[128+i*8+4]=bflo(q.z); abi[128+i*8+5]=bfhi(q.z);
            abi[128+i*8+6]=bflo(q.w); abi[128+i*8+7]=bfhi(q.w);
        }

        float acc2 = bias2;
#pragma unroll 1
        for (int j = 0; j < 128; j += 4) {
            float a0 = sh[24576+j+0], a1 = sh[24576+j+1], a2 = sh[24576+j+2], a3 = sh[24576+j+3];
#pragma unroll
            for (int k = 0; k < 192; ++k) {
                const float v = abi[k];
                a0 = fmaf(v, sh[(j+0)*192+k], a0);
                a1 = fmaf(v, sh[(j+1)*192+k], a1);
                a2 = fmaf(v, sh[(j+2)*192+k], a2);
                a3 = fmaf(v, sh[(j+3)*192+k], a3);
            }
            acc2 = fmaf(fmaxf(a0, 0.f), sh[24704+j+0], acc2);
            acc2 = fmaf(fmaxf(a1, 0.f), sh[24704+j+1], acc2);
            acc2 = fmaf(fmaxf(a2, 0.f), sh[24704+j+2], acc2);
            acc2 = fmaf(fmaxf(a3, 0.f), sh[24704+j+3], acc2);
        }
        out[gpos] = acc2;
    }
}

extern "C" void kernel_launch(void* const* d_in, const int* in_sizes, int n_in,
                              void* d_out, int out_size, void* d_ws, size_t ws_size,
                              hipStream_t stream)
{
    const float* x     = (const float*)d_in[0];
    const float* t     = (const float*)d_in[1];
    const float* mtok  = (const float*)d_in[2];
    const float* te_w1 = (const float*)d_in[3];
    const float* te_b1 = (const float*)d_in[4];
    const float* te_w2 = (const float*)d_in[5];
    const float* te_b2 = (const float*)d_in[6];
    const float* fpw   = (const float*)d_in[7];
    const float* fpb   = (const float*)d_in[8];
    const float* bpw   = (const float*)d_in[9];
    const float* bpb   = (const float*)d_in[10];
    const float* fwz   = (const float*)d_in[11];
    const float* fbz   = (const float*)d_in[12];
    const float* fwh   = (const float*)d_in[13];
    const float* fbh   = (const float*)d_in[14];
    const float* bwz   = (const float*)d_in[15];
    const float* bbz   = (const float*)d_in[16];
    const float* bwh   = (const float*)d_in[17];
    const float* bbh   = (const float*)d_in[18];
    const float* w1    = (const float*)d_in[19];
    const float* b1    = (const float*)d_in[20];
    const float* w2    = (const float*)d_in[21];
    const float* b2    = (const float*)d_in[22];

    // Per-batch-row workspace footprint (bytes):
    //   abf+abb : 2 * 64*2048*4 = 1,048,576
    //   hf+hb   : 2 * 2048*64*2 =   524,288
    //   tenc    :     2048*64*2 =   262,144
    const size_t per_b = 1835008ull;
    int Bg = NB;
    while ((size_t)Bg * per_b > ws_size && Bg > 1) Bg >>= 1;
    const int nG = NB / Bg;

    char* ws = (char*)d_ws;
    uint32_t*       abf  = (uint32_t*)(ws);
    uint32_t*       abb  = abf + (size_t)Bg * 64 * NL;
    unsigned short* hf   = (unsigned short*)(abb + (size_t)Bg * 64 * NL);
    unsigned short* hb   = hf + (size_t)Bg * NL * 64;
    unsigned short* tenc = hb + (size_t)Bg * NL * 64;

    for (int g = 0; g < nG; ++g) {
        const int b0 = g * Bg;

        prep_kernel<<<2 * Bg, 256, 0, stream>>>(
            x, t, mtok, te_w1, te_b1, te_w2, te_b2,
            fpw, fpb, bpw, bpb, fwz, fbz, fwh, fbh, bwz, bbz, bwh, bbh,
            b0, tenc, abf, abb);

        scan_kernel<<<2 * Bg, 64, 0, stream>>>(abf, abb, Bg, hf, hb);

        head_kernel<<<2 * Bg, 256, 0, stream>>>(
            x, tenc, hf, hb, w1, b1, w2, b2, b0, (float*)d_out);
    }
}

// Round 4
// 570.748 us; speedup vs baseline: 4.4889x; 4.4889x over previous
//
#include <hip/hip_runtime.h>
#include <stdint.h>

// Problem constants (B=256, L=2048, H=64, TE=64)
#define NB 256
#define NL 2048

typedef __attribute__((ext_vector_type(8))) short short8;
typedef __attribute__((ext_vector_type(4))) float f32x4;
#define MFMA16(a,b,c) __builtin_amdgcn_mfma_f32_16x16x32_bf16(a,b,c,0,0,0)

// ---------- bf16 helpers (manual, RNE) ----------
static __device__ __forceinline__ unsigned short f2bf(float f) {
    union { float f; uint32_t u; } v; v.f = f;
    uint32_t u = v.u;
    uint32_t r = u + 0x7fffu + ((u >> 16) & 1u);
    return (unsigned short)(r >> 16);
}
static __device__ __forceinline__ float bflo(uint32_t u) {
    union { uint32_t u; float f; } v; v.u = u << 16; return v.f;
}
static __device__ __forceinline__ float bfhi(uint32_t u) {
    union { uint32_t u; float f; } v; v.u = u & 0xffff0000u; return v.f;
}
static __device__ __forceinline__ uint32_t pack2(float lo, float hi) {
    return ((uint32_t)f2bf(hi) << 16) | (uint32_t)f2bf(lo);
}
static __device__ __forceinline__ short8 frag8(const float* p) {
    short8 r;
#pragma unroll
    for (int j = 0; j < 8; ++j) r[j] = (short)f2bf(p[j]);
    return r;
}

// =====================================================================
// kernel 1: MFMA prep — time-MLP + proj + gates
// block = 256 thr (4 waves), NCH=4 chunks of 64 positions; grid = 8*Bg
// =====================================================================
__global__ __launch_bounds__(256, 2) void prep_kernel(
    const float* __restrict__ x, const float* __restrict__ t,
    const float* __restrict__ mtok,
    const float* __restrict__ te_w1, const float* __restrict__ te_b1,
    const float* __restrict__ te_w2, const float* __restrict__ te_b2,
    const float* __restrict__ fpw, const float* __restrict__ fpb,
    const float* __restrict__ bpw, const float* __restrict__ bpb,
    const float* __restrict__ fwz, const float* __restrict__ fbz,
    const float* __restrict__ fwh, const float* __restrict__ fbh,
    const float* __restrict__ bwz, const float* __restrict__ bbz,
    const float* __restrict__ bwh, const float* __restrict__ bbh,
    int b0,
    unsigned short* __restrict__ tenc_out,   // [Bg*L,64] bf16 (group-local)
    uint32_t* __restrict__ abf,              // [Bg*64, L] packed (a lo, b hi)
    uint32_t* __restrict__ abb)
{
    __shared__ __align__(16) unsigned short s_te1[64*72];     //  9216 B
    __shared__ __align__(16) unsigned short s_tenc[64*72];    //  9216 B
    __shared__ __align__(16) unsigned short s_inp[2][64*72];  // 18432 B
    __shared__ __align__(16) unsigned short s_xa[64*40];      //  5120 B
    __shared__ __align__(16) uint32_t       s_zt[2][64*67];   // 34304 B (z lo, tanh hi)

    const int tid = threadIdx.x;
    const int w   = tid >> 6;     // wave 0..3
    const int l   = tid & 63;
    const int lq  = l >> 4;       // quad
    const int ln  = l & 15;

    // ---- weight B-fragments (once per block; B[k][n]: n=lane&15, k=quad*8+j) ----
    short8 bte[2];
    {
        const int o = w*16 + ln;
        const float* row = te_w2 + o*64;
#pragma unroll
        for (int ks = 0; ks < 2; ++ks) bte[ks] = frag8(row + lq*8 + ks*32);
    }
    short8 bpj[2][3];
#pragma unroll
    for (int p = 0; p < 2; ++p) {
        const int g = 2*w + p;
        const float* PW = (g < 4) ? fpw : bpw;
        const int o = (g & 3)*16 + ln;
        const float* row = PW + o*67;
#pragma unroll
        for (int ks = 0; ks < 2; ++ks) {
            float tmp[8];
#pragma unroll
            for (int j = 0; j < 8; ++j) tmp[j] = row[3 + lq*8 + ks*32 + j];
            bpj[p][ks] = frag8(tmp);
        }
        {   // K-step 2: cols 64..66 = x0,x1,mc weights, rest 0
            float tmp[8];
#pragma unroll
            for (int j = 0; j < 8; ++j) tmp[j] = (lq == 0 && j < 3) ? row[j] : 0.f;
            bpj[p][2] = frag8(tmp);
        }
    }
    short8 bg[4][2];
    {
        const float* GW = (w == 0) ? fwz : (w == 1) ? fwh : (w == 2) ? bwz : bwh;
#pragma unroll
        for (int nt = 0; nt < 4; ++nt) {
            const float* row = GW + (nt*16 + ln)*64;
#pragma unroll
            for (int ks = 0; ks < 2; ++ks) bg[nt][ks] = frag8(row + lq*8 + ks*32);
        }
    }
    // per-lane biases
    const float bias_te = te_b2[w*16 + ln];
    float bias_pj[2];
#pragma unroll
    for (int p = 0; p < 2; ++p) {
        const int g = 2*w + p;
        bias_pj[p] = ((g < 4) ? fpb : bpb)[(g & 3)*16 + ln];
    }
    float bias_g[4];
    {
        const float* GB = (w == 0) ? fbz : (w == 1) ? fbh : (w == 2) ? bbz : bbh;
#pragma unroll
        for (int nt = 0; nt < 4; ++nt) bias_g[nt] = GB[nt*16 + ln];
    }
    const float mt0 = mtok[0], mt1 = mtok[1];

    // zero the xa tile once (cols 3..31 stay 0; cols 0..2 rewritten per chunk)
    for (int i = tid; i < 64*40/2; i += 256) ((uint32_t*)s_xa)[i] = 0;

    const int baseposl = blockIdx.x * 256;   // 4 chunks x 64

#pragma unroll 1
    for (int ch = 0; ch < 4; ++ch) {
        const int chbase = baseposl + ch*64;
        const int ll0   = chbase & 2047;
        const int bl    = chbase >> 11;
        const int gbase = (b0 << 11) + chbase;

        // ---- phase 0: stage te1 + xa ----
        {
            const int pos = tid & 63;
            const float tv = t[gbase + pos];
            const int k0 = (tid >> 6) * 16;                   // wave-uniform
            uint32_t* dst = (uint32_t*)(s_te1 + pos*72 + k0);
#pragma unroll
            for (int kk = 0; kk < 16; kk += 2) {
                float v0 = fmaxf(fmaf(tv, te_w1[k0+kk],   te_b1[k0+kk]),   0.f);
                float v1 = fmaxf(fmaf(tv, te_w1[k0+kk+1], te_b1[k0+kk+1]), 0.f);
                dst[kk >> 1] = pack2(v0, v1);
            }
            if (tid < 64) {
                const float* xp = x + (size_t)(gbase + tid)*3;
                const float mc = xp[2];
                const float x0 = (mc == 0.f) ? mt0 : xp[0];
                const float x1 = (mc == 0.f) ? mt1 : xp[1];
                uint32_t* xr = (uint32_t*)(s_xa + tid*40);
                xr[0] = pack2(x0, x1);
                xr[1] = pack2(mc, 0.f);
            }
        }
        __syncthreads();

        // ---- GEMM1: tenc = te1 * te_w2^T + b ----
        {
            const int o = w*16 + ln;
#pragma unroll
            for (int mt = 0; mt < 4; ++mt) {
                f32x4 c = {0.f, 0.f, 0.f, 0.f};
#pragma unroll
                for (int ks = 0; ks < 2; ++ks) {
                    const short8 a = *(const short8*)(s_te1 + (mt*16+ln)*72 + lq*8 + ks*32);
                    c = MFMA16(a, bte[ks], c);
                }
#pragma unroll
                for (int r = 0; r < 4; ++r) {
                    const int m = mt*16 + lq*4 + r;
                    s_tenc[m*72 + o] = f2bf(c[r] + bias_te);
                }
            }
        }
        __syncthreads();

        // ---- GEMM2: inp_{f,b} = [tenc | x3 | 0] * pw'^T + pb ----
        {
#pragma unroll
            for (int mt = 0; mt < 4; ++mt) {
                short8 a0 = *(const short8*)(s_tenc + (mt*16+ln)*72 + lq*8);
                short8 a1 = *(const short8*)(s_tenc + (mt*16+ln)*72 + lq*8 + 32);
                short8 a2 = *(const short8*)(s_xa   + (mt*16+ln)*40 + lq*8);
#pragma unroll
                for (int p = 0; p < 2; ++p) {
                    const int g = 2*w + p;
                    const int dir = g >> 2;
                    const int o = (g & 3)*16 + ln;
                    f32x4 c = {0.f, 0.f, 0.f, 0.f};
                    c = MFMA16(a0, bpj[p][0], c);
                    c = MFMA16(a1, bpj[p][1], c);
                    c = MFMA16(a2, bpj[p][2], c);
#pragma unroll
                    for (int r = 0; r < 4; ++r) {
                        const int m = mt*16 + lq*4 + r;
                        s_inp[dir][m*72 + o] = f2bf(c[r] + bias_pj[p]);
                    }
                }
            }
        }
        __syncthreads();

        // ---- GEMM3: gates (wave w -> fwz/fwh/bwz/bwh) ----
        {
            const int dir = w >> 1;
#pragma unroll
            for (int mt = 0; mt < 4; ++mt) {
                short8 a0 = *(const short8*)(s_inp[dir] + (mt*16+ln)*72 + lq*8);
                short8 a1 = *(const short8*)(s_inp[dir] + (mt*16+ln)*72 + lq*8 + 32);
#pragma unroll
                for (int nt = 0; nt < 4; ++nt) {
                    f32x4 c = {0.f, 0.f, 0.f, 0.f};
                    c = MFMA16(a0, bg[nt][0], c);
                    c = MFMA16(a1, bg[nt][1], c);
                    const int o = nt*16 + ln;
#pragma unroll
                    for (int r = 0; r < 4; ++r) {
                        const int m = mt*16 + lq*4 + r;
                        const float av = c[r] + bias_g[nt];
                        unsigned short* h2 = (unsigned short*)&s_zt[dir][m*67 + o];
                        if (w & 1) {                 // h-tilde -> tanh, high half
                            const float cc = fminf(fmaxf(av, -15.f), 15.f);
                            const float e  = __expf(2.f * cc);
                            h2[1] = f2bf((e - 1.f) / (e + 1.f));
                        } else {                     // z -> sigmoid, low half
                            h2[0] = f2bf(1.f / (1.f + __expf(-av)));
                        }
                    }
                }
            }
        }
        __syncthreads();

        // ---- writer: (a,b) packed + tenc_out, coalesced ----
        {
#pragma unroll 1
            for (int d = 0; d < 2; ++d) {
                uint32_t* dst = (d ? abb : abf) + (size_t)(bl*64)*NL + ll0;
                const uint32_t* src = s_zt[d];
#pragma unroll
                for (int rep = 0; rep < 16; ++rep) {
                    const int idx = rep*256 + tid;
                    const int o = idx >> 6, row = idx & 63;
                    const uint32_t u = src[row*67 + o];
                    const float z = bflo(u), th = bfhi(u);
                    dst[(size_t)o*NL + row] = pack2(1.f - z, z*th);
                }
            }
            uint32_t* tdst = (uint32_t*)tenc_out + (size_t)chbase * 32;
            const uint32_t* tsrc = (const uint32_t*)s_tenc;
#pragma unroll
            for (int rep = 0; rep < 8; ++rep) {
                const int idx = rep*256 + tid;
                const int row = idx >> 5, op = idx & 31;
                tdst[row*32 + op] = tsrc[row*36 + op];
            }
        }
        __syncthreads();
    }
}

// ---------- kernel 2: 2*Bg*64 independent linear scans (unchanged) ----------
__global__ __launch_bounds__(64) void scan_kernel(
    const uint32_t* __restrict__ abf, const uint32_t* __restrict__ abb,
    int Bg,
    unsigned short* __restrict__ hf, unsigned short* __restrict__ hb) // [b_l][l][h] bf16
{
    const int tid = blockIdx.x * 64 + threadIdx.x;
    const int nfw = Bg * 64;
    const int dir = (tid >= nfw) ? 1 : 0;
    const int bh  = tid - dir * nfw;
    const int bl  = bh >> 6;
    const int hh  = bh & 63;

    const uint32_t* ab = (dir ? abb : abf) + (size_t)bh * NL;
    unsigned short* out = (dir ? hb : hf) + (size_t)bl * NL * 64 + hh;

    float hv = 0.f;
    if (dir == 0) {
#pragma unroll 1
        for (int l0 = 0; l0 < NL; l0 += 32) {
            const uint4* p = (const uint4*)(ab + l0);
            uint4 v[8];
#pragma unroll
            for (int i = 0; i < 8; ++i) v[i] = p[i];
            uint32_t q[32];
#pragma unroll
            for (int i = 0; i < 8; ++i) {
                q[4*i+0]=v[i].x; q[4*i+1]=v[i].y; q[4*i+2]=v[i].z; q[4*i+3]=v[i].w;
            }
            unsigned short* op = out + (size_t)l0 * 64;
#pragma unroll
            for (int i = 0; i < 32; ++i) {
                *op = f2bf(hv); op += 64;
                hv = fmaf(bflo(q[i]), hv, bfhi(q[i]));
            }
        }
    } else {
#pragma unroll 1
        for (int l0 = NL - 32; l0 >= 0; l0 -= 32) {
            const uint4* p = (const uint4*)(ab + l0);
            uint4 v[8];
#pragma unroll
            for (int i = 0; i < 8; ++i) v[i] = p[i];
            uint32_t q[32];
#pragma unroll
            for (int i = 0; i < 8; ++i) {
                q[4*i+0]=v[i].x; q[4*i+1]=v[i].y; q[4*i+2]=v[i].z; q[4*i+3]=v[i].w;
            }
            unsigned short* op = out + (size_t)(l0 + 31) * 64;
#pragma unroll
            for (int i = 31; i >= 0; --i) {
                *op = f2bf(hv); op -= 64;
                hv = fmaf(bflo(q[i]), hv, bfhi(q[i]));
            }
        }
    }
}

// =====================================================================
// kernel 3: MFMA head — [hf|hb|tenc](192) -> 128 relu -> 1
// block = 256 thr, 4 chunks of 64 positions; grid = 8*Bg
// =====================================================================
__global__ __launch_bounds__(256, 2) void head_kernel(
    const float* __restrict__ x,
    const unsigned short* __restrict__ tenc,
    const unsigned short* __restrict__ hf, const unsigned short* __restrict__ hb,
    const float* __restrict__ w1, const float* __restrict__ b1,  // [128,192],[128]
    const float* __restrict__ w2, const float* __restrict__ b2,  // [1,128],[1]
    int b0,
    float* __restrict__ out)
{
    __shared__ __align__(16) unsigned short s_a[64*200];   // 25600 B
    __shared__ float s_hid[64*133];                        // 34048 B
    __shared__ float s_pac[256];

    const int tid = threadIdx.x;
    const int w   = tid >> 6;
    const int l   = tid & 63;
    const int lq  = l >> 4;
    const int ln  = l & 15;

    // ---- W1 fragments + per-lane b1/w2 ----
    short8 bw1[2][6];
    float b1v[2], w2v[2];
#pragma unroll
    for (int p = 0; p < 2; ++p) {
        const int o = (2*w + p)*16 + ln;
        const float* row = w1 + o*192;
#pragma unroll
        for (int ks = 0; ks < 6; ++ks) bw1[p][ks] = frag8(row + lq*8 + ks*32);
        b1v[p] = b1[o];
        w2v[p] = w2[o];
    }
    const float bias2 = b2[0];

    const int baseposl = blockIdx.x * 256;

#pragma unroll 1
    for (int ch = 0; ch < 4; ++ch) {
        const int chbase = baseposl + ch*64;
        const int ll0   = chbase & 2047;
        const int bl    = chbase >> 11;
        const int gbase = (b0 << 11) + chbase;
        const size_t rowbase = (size_t)bl * NL * 64;

        // ---- stage A tile [64 pos x 192] bf16 ----
#pragma unroll 1
        for (int seg = 0; seg < 3; ++seg) {
#pragma unroll
            for (int rep = 0; rep < 8; ++rep) {
                const int idx = rep*256 + tid;
                const int row = idx >> 5, c = idx & 31;
                const float mc = x[(size_t)(gbase + row)*3 + 2];
                const bool unm = mc > 0.f;
                const uint32_t* src;
                if (seg == 0)      src = (const uint32_t*)(hf + rowbase + (size_t)(unm ? (ll0+row) : (NL-1))*64);
                else if (seg == 1) src = (const uint32_t*)(hb + rowbase + (size_t)(unm ? (ll0+row) : 0)*64);
                else               src = (const uint32_t*)(tenc + (size_t)(chbase + row)*64);
                ((uint32_t*)s_a)[row*100 + seg*32 + c] = src[c];
            }
        }
        __syncthreads();

        // ---- GEMM1 + premultiplied-hid epilogue ----
        {
#pragma unroll
            for (int mt = 0; mt < 4; ++mt) {
                short8 af[6];
#pragma unroll
                for (int ks = 0; ks < 6; ++ks)
                    af[ks] = *(const short8*)(s_a + (mt*16+ln)*200 + lq*8 + ks*32);
#pragma unroll
                for (int p = 0; p < 2; ++p) {
                    f32x4 c = {0.f, 0.f, 0.f, 0.f};
#pragma unroll
                    for (int ks = 0; ks < 6; ++ks) c = MFMA16(af[ks], bw1[p][ks], c);
                    const int o = (2*w + p)*16 + ln;
#pragma unroll
                    for (int r = 0; r < 4; ++r) {
                        const int m = mt*16 + lq*4 + r;
                        s_hid[m*133 + o] = fmaxf(c[r] + b1v[p], 0.f) * w2v[p];
                    }
                }
            }
        }
        __syncthreads();

        // ---- GEMM2: row sums (4 threads per row, rotated to dodge banks) ----
        {
            const int m = tid >> 2, part = tid & 3;
            const float* hrow = s_hid + m*133;
            float s = 0.f;
#pragma unroll
            for (int i = 0; i < 32; ++i) {
                const int c = part*32 + ((i + part*8) & 31);
                s += hrow[c];
            }
            s_pac[tid] = s;
        }
        __syncthreads();
        if (tid < 64) {
            out[gbase + tid] = s_pac[tid*4] + s_pac[tid*4+1] + s_pac[tid*4+2] + s_pac[tid*4+3] + bias2;
        }
        __syncthreads();
    }
}

extern "C" void kernel_launch(void* const* d_in, const int* in_sizes, int n_in,
                              void* d_out, int out_size, void* d_ws, size_t ws_size,
                              hipStream_t stream)
{
    const float* x     = (const float*)d_in[0];
    const float* t     = (const float*)d_in[1];
    const float* mtok  = (const float*)d_in[2];
    const float* te_w1 = (const float*)d_in[3];
    const float* te_b1 = (const float*)d_in[4];
    const float* te_w2 = (const float*)d_in[5];
    const float* te_b2 = (const float*)d_in[6];
    const float* fpw   = (const float*)d_in[7];
    const float* fpb   = (const float*)d_in[8];
    const float* bpw   = (const float*)d_in[9];
    const float* bpb   = (const float*)d_in[10];
    const float* fwz   = (const float*)d_in[11];
    const float* fbz   = (const float*)d_in[12];
    const float* fwh   = (const float*)d_in[13];
    const float* fbh   = (const float*)d_in[14];
    const float* bwz   = (const float*)d_in[15];
    const float* bbz   = (const float*)d_in[16];
    const float* bwh   = (const float*)d_in[17];
    const float* bbh   = (const float*)d_in[18];
    const float* w1    = (const float*)d_in[19];
    const float* b1    = (const float*)d_in[20];
    const float* w2    = (const float*)d_in[21];
    const float* b2    = (const float*)d_in[22];

    // Per-batch-row workspace footprint (bytes):
    //   abf+abb : 2 * 64*2048*4 = 1,048,576
    //   hf+hb   : 2 * 2048*64*2 =   524,288
    //   tenc    :     2048*64*2 =   262,144
    const size_t per_b = 1835008ull;
    int Bg = NB;
    while ((size_t)Bg * per_b > ws_size && Bg > 1) Bg >>= 1;
    const int nG = NB / Bg;

    char* ws = (char*)d_ws;
    uint32_t*       abf  = (uint32_t*)(ws);
    uint32_t*       abb  = abf + (size_t)Bg * 64 * NL;
    unsigned short* hf   = (unsigned short*)(abb + (size_t)Bg * 64 * NL);
    unsigned short* hb   = hf + (size_t)Bg * NL * 64;
    unsigned short* tenc = hb + (size_t)Bg * NL * 64;

    for (int g = 0; g < nG; ++g) {
        const int b0 = g * Bg;

        prep_kernel<<<8 * Bg, 256, 0, stream>>>(
            x, t, mtok, te_w1, te_b1, te_w2, te_b2,
            fpw, fpb, bpw, bpb, fwz, fbz, fwh, fbh, bwz, bbz, bwh, bbh,
            b0, tenc, abf, abb);

        scan_kernel<<<2 * Bg, 64, 0, stream>>>(abf, abb, Bg, hf, hb);

        head_kernel<<<8 * Bg, 256, 0, stream>>>(
            x, tenc, hf, hb, w1, b1, w2, b2, b0, (float*)d_out);
    }
}